// Round 8
// baseline (357.391 us; speedup 1.0000x reference)
//
#include <hip/hip_runtime.h>
#include <hip/hip_bf16.h>

// ChildSumTreeLSTM, complete binary tree heap layout (children of n: 2n+1, 2n+2).
// R8: x precomputed to bf16 once (convx). k1 = 256 persistent blocks x 8
// subtrees (d16..d11); per-subtree x (63 rows, 16KB bf16) register-prefetched
// (2 uint4/thread) one subtree ahead -> staging HBM latency hidden behind the
// 7 compute phases. Intermediate h/c in LDS; cnt=1 levels write the root row
// straight to global from the epilogue (one fewer phase). B (wave's 16-col
// slice of all 4 gates, K=256) register-resident: 32 short8. k2: d10..d5
// (32 blocks), k3: d4..d0 + projection (1 block), both staged from bf16 x.
// Bsw = fragment-stream-ordered [W/2 | U] (f-gate W unhalved), gates
// [i,o,u,f]; child row r computes [x_par; h_child]@B^T, epilogue sums row
// pairs in-lane. c fp32, h bf16.

#define DEPTH 17
#define NTREE ((1 << DEPTH) - 1)  // 131071
#define DIM 128
#define XSTR 132  // LDS bf16 row stride (shorts), 264 B
#define HSTR 132
#define CSTR 132  // LDS f32 row stride (floats)

typedef __attribute__((ext_vector_type(8))) short short8;
typedef __attribute__((ext_vector_type(4))) float float4v;

__device__ __forceinline__ float sigm(float v) {
    return __fdividef(1.0f, 1.0f + __expf(-v));
}
__device__ __forceinline__ float ftanh(float v) {
    v = fminf(15.0f, fmaxf(-15.0f, v));
    float e = __expf(2.0f * v);
    return __fdividef(e - 1.0f, e + 1.0f);
}

__device__ __forceinline__ unsigned short f2bf(float f) {
    union { float f; unsigned u; } a; a.f = f;
    unsigned u = a.u;
    return (unsigned short)((u + 0x7fffu + ((u >> 16) & 1u)) >> 16);  // RNE
}
__device__ __forceinline__ float bf2f(unsigned short s) {
    union { unsigned u; float f; } a; a.u = ((unsigned)s) << 16;
    return a.f;
}

struct WPtrs {
    const float* W[4];  const float* U[4];
    const float* bW[4]; const float* bU[4];
};

// Bsw[w][ks][g][lane][j] (w:8, ks:8, g:4, lane:64, j:8) = fragment-stream order.
// Element = B4[col = g*128 + w*16 + (lane&15)][k = ks*32 + (lane>>4)*8 + j],
// where B4 = [W * (g==3 ? 1 : 0.5) | U].
__global__ __launch_bounds__(256) void prep_kernel(WPtrs p, unsigned short* __restrict__ Bsw,
                                                   float* __restrict__ biasWU, float* __restrict__ biasL) {
    int idx = blockIdx.x * 256 + threadIdx.x;  // 0 .. 131071
    int j = idx & 7;
    int lane = (idx >> 3) & 63;
    int g = (idx >> 9) & 3;
    int ks = (idx >> 11) & 7;
    int w = idx >> 14;
    int L = lane & 15, q = lane >> 4;
    int c = w * 16 + L;
    int k = ks * 32 + q * 8 + j;
    float v = (k < 128) ? p.W[g][c * 128 + k] * (g == 3 ? 1.0f : 0.5f)
                        : p.U[g][c * 128 + (k - 128)];
    Bsw[idx] = f2bf(v);
    if (idx < 512) {
        int gg = idx >> 7, cc = idx & 127;
        biasWU[idx] = p.bW[gg][cc] + p.bU[gg][cc];
        biasL[idx]  = p.bW[gg][cc];
    }
}

__global__ __launch_bounds__(256) void convx_kernel(const float* __restrict__ x,
                                                    unsigned short* __restrict__ xbf, int n4) {
    int i = blockIdx.x * 256 + threadIdx.x;
    int stride = gridDim.x * 256;
    for (; i < n4; i += stride) {
        float4 v = ((const float4*)x)[i];
        ushort4 o;
        o.x = f2bf(v.x); o.y = f2bf(v.y); o.z = f2bf(v.z); o.w = f2bf(v.w);
        ((ushort4*)xbf)[i] = o;
    }
}

// One internal level. Children h (MFMA A-frags) + c (epilogue) from LDS (!GCH)
// or global rows at cb (GCH). Outputs through (ho, ho_str)/(co, co_str) --
// LDS buffers or direct global rows (cnt==1 root levels).
template <bool GCH>
__device__ __forceinline__ void internal_level(
    const unsigned short* xc,
    const unsigned short* hin_l, const float* cin_l,
    const unsigned short* __restrict__ hin_g, const float* __restrict__ cin_g, long cb,
    unsigned short* ho, int ho_str, float* co, int co_str, int cnt,
    const short8 (&b)[32], const float* __restrict__ biasWU,
    int L, int q, int ch) {
    const int rows = 2 * cnt;
    const int mt = (rows + 15) >> 4;
    for (int mc = 0; mc < mt; mc += 2) {
        const int mm_n = (mt - mc >= 2) ? 2 : 1;
        float4v acc[2][4];
#pragma unroll
        for (int mm = 0; mm < 2; ++mm)
#pragma unroll
            for (int g = 0; g < 4; ++g) acc[mm][g] = (float4v){0.f, 0.f, 0.f, 0.f};

#pragma unroll
        for (int ks = 0; ks < 8; ++ks) {
            const int kk = ks * 32;
            short8 a[2];
#pragma unroll
            for (int mm = 0; mm < 2; ++mm) {
                if (mm < mm_n) {
                    if (kk < 128) {
                        int xr = 8 * (mc + mm) + (L >> 1);
                        if (xr >= cnt) xr = 0;  // garbage row clamp (masked later)
                        a[mm] = *(const short8*)(xc + xr * XSTR + kk + q * 8);
                    } else if (!GCH) {
                        a[mm] = *(const short8*)(hin_l + (16 * (mc + mm) + L) * HSTR + (kk - 128) + q * 8);
                    } else {
                        a[mm] = *(const short8*)(hin_g + (size_t)(cb + 16 * (mc + mm) + L) * DIM + (kk - 128) + q * 8);
                    }
                }
            }
#pragma unroll
            for (int g = 0; g < 4; ++g)
#pragma unroll
                for (int mm = 0; mm < 2; ++mm)
                    if (mm < mm_n)
                        acc[mm][g] = __builtin_amdgcn_mfma_f32_16x16x32_bf16(a[mm], b[ks * 4 + g], acc[mm][g], 0, 0, 0);
        }

#pragma unroll
        for (int mm = 0; mm < 2; ++mm)
#pragma unroll
            for (int e = 0; e < 2; ++e) {
                if (mm < mm_n) {
                    const int nl = 8 * (mc + mm) + 2 * q + e;
                    if (nl < cnt) {
                        const int r0 = 2 * e, r1 = 2 * e + 1;
                        float iv = sigm(acc[mm][0][r0] + acc[mm][0][r1] + biasWU[ch]);
                        float ov = sigm(acc[mm][1][r0] + acc[mm][1][r1] + biasWU[128 + ch]);
                        float uv = ftanh(acc[mm][2][r0] + acc[mm][2][r1] + biasWU[256 + ch]);
                        float fl = sigm(acc[mm][3][r0] + biasWU[384 + ch]);
                        float fr = sigm(acc[mm][3][r1] + biasWU[384 + ch]);
                        float cl, cr;
                        if (!GCH) {
                            cl = cin_l[(2 * nl) * CSTR + ch];
                            cr = cin_l[(2 * nl + 1) * CSTR + ch];
                        } else {
                            cl = cin_g[(size_t)(cb + 2 * nl) * DIM + ch];
                            cr = cin_g[(size_t)(cb + 2 * nl + 1) * DIM + ch];
                        }
                        float cv = iv * uv + fl * cl + fr * cr;
                        co[nl * co_str + ch] = cv;
                        ho[nl * ho_str + ch] = f2bf(ov * ftanh(cv));
                    }
                }
            }
    }
}

// True-leaf level: 32 nodes (2 m-tiles), K=128 (W half), gates i,o,u; logit = 2*acc + bW.
__device__ __forceinline__ void leaf_level(
    const unsigned short* xc, unsigned short* ho, float* co,
    const short8 (&b)[32], const float* __restrict__ biasL,
    int L, int q, int ch) {
    float4v acc[2][3];
#pragma unroll
    for (int mm = 0; mm < 2; ++mm)
#pragma unroll
        for (int g = 0; g < 3; ++g) acc[mm][g] = (float4v){0.f, 0.f, 0.f, 0.f};
#pragma unroll
    for (int ks = 0; ks < 4; ++ks) {
        short8 a[2];
        a[0] = *(const short8*)(xc + L * XSTR + ks * 32 + q * 8);
        a[1] = *(const short8*)(xc + (16 + L) * XSTR + ks * 32 + q * 8);
#pragma unroll
        for (int g = 0; g < 3; ++g)
#pragma unroll
            for (int mm = 0; mm < 2; ++mm)
                acc[mm][g] = __builtin_amdgcn_mfma_f32_16x16x32_bf16(a[mm], b[ks * 4 + g], acc[mm][g], 0, 0, 0);
    }
#pragma unroll
    for (int mm = 0; mm < 2; ++mm)
#pragma unroll
        for (int r = 0; r < 4; ++r) {
            const int nl = 16 * mm + q * 4 + r;
            float iv = sigm(2.f * acc[mm][0][r] + biasL[ch]);
            float ov = sigm(2.f * acc[mm][1][r] + biasL[128 + ch]);
            float uv = ftanh(2.f * acc[mm][2][r] + biasL[256 + ch]);
            float cv = iv * uv;
            co[nl * CSTR + ch] = cv;
            ho[nl * HSTR + ch] = f2bf(ov * ftanh(cv));
        }
}

// K1: persistent. 256 blocks x 8 subtrees (d16..d11). x register-prefetched one
// subtree ahead (63 rows bf16 = 1008 uint4 granules = 2/thread).
__global__ __launch_bounds__(512, 2) void k1_kernel(
    const unsigned short* __restrict__ xbf, const unsigned short* __restrict__ Bsw,
    const float* __restrict__ biasL, const float* __restrict__ biasWU,
    unsigned short* __restrict__ hbf, float* __restrict__ cbuf) {
    __shared__ __align__(16) unsigned short xs[63 * XSTR];
    __shared__ __align__(16) unsigned short hA[32 * HSTR];
    __shared__ __align__(16) unsigned short hB[16 * HSTR];
    __shared__ __align__(16) float cA[32 * CSTR];
    __shared__ __align__(16) float cB[16 * CSTR];

    const int tid = threadIdx.x;
    const int w = tid >> 6, lane = tid & 63, L = lane & 15, q = lane >> 4;
    const int ch = w * 16 + L;

    short8 b[32];
#pragma unroll
    for (int t = 0; t < 32; ++t)
        b[t] = *(const short8*)(Bsw + ((size_t)w << 14) + (t << 9) + lane * 8);

    // row -> (level, global node) map for the 63 staged x rows of subtree t:
    //   u = 63-row; l = clz(u)-26; r = row - (64 - (64>>l));
    //   node = (2^(16-l) - 1) + t*(32>>l) + r
    uint4 pf[2];
    {
        const long t0 = blockIdx.x;
#pragma unroll
        for (int k = 0; k < 2; ++k) {
            const int i = tid + 512 * k;
            if (i < 1008) {
                const int row = i >> 4, g = i & 15;
                const int l = __clz(63 - row) - 26;
                const long node = ((1L << (16 - l)) - 1) + t0 * (32 >> l) + (row - (64 - (64 >> l)));
                pf[k] = *(const uint4*)(xbf + (size_t)node * DIM + g * 8);
            }
        }
    }

    for (int it = 0; it < 8; ++it) {
        const long t = (long)it * 256 + blockIdx.x;

        // publish prefetched x into LDS
#pragma unroll
        for (int k = 0; k < 2; ++k) {
            const int i = tid + 512 * k;
            if (i < 1008) {
                const int row = i >> 4, g = i & 15;
                *(uint4*)(xs + row * XSTR + g * 8) = pf[k];
            }
        }
        __syncthreads();

        // issue next subtree's prefetch (in flight during all compute phases)
        if (it < 7) {
            const long tn = t + 256;
#pragma unroll
            for (int k = 0; k < 2; ++k) {
                const int i = tid + 512 * k;
                if (i < 1008) {
                    const int row = i >> 4, g = i & 15;
                    const int l = __clz(63 - row) - 26;
                    const long node = ((1L << (16 - l)) - 1) + tn * (32 >> l) + (row - (64 - (64 >> l)));
                    pf[k] = *(const uint4*)(xbf + (size_t)node * DIM + g * 8);
                }
            }
        }

        leaf_level(xs, hA, cA, b, biasL, L, q, ch);
        __syncthreads();

        const unsigned short* hin = hA;
        const float* cin = cA;
        int xoff = 32;
#pragma unroll
        for (int l = 1; l < 5; ++l) {
            const int cnt = 32 >> l;
            unsigned short* ho = (l & 1) ? hB : hA;
            float* co = (l & 1) ? cB : cA;
            internal_level<false>(xs + xoff * XSTR, hin, cin, nullptr, nullptr, 0,
                                  ho, HSTR, co, CSTR, cnt, b, biasWU, L, q, ch);
            __syncthreads();
            hin = ho; cin = co; xoff += cnt;
        }

        // l=5 (cnt=1): subtree root written straight to global
        const long ob = 2047 + t;
        internal_level<false>(xs + 62 * XSTR, hin, cin, nullptr, nullptr, 0,
                              hbf + (size_t)ob * DIM, DIM,
                              cbuf + (size_t)ob * DIM, DIM, 1, b, biasWU, L, q, ch);
        __syncthreads();
    }
}

// K2/K3: fused subtree; level-0 children from global rows [cb, cb+2C).
// K2: C=32, NL=6, d0=10 (32 blocks, root -> global). K3: C=16, NL=5, d0=4, PROJ.
template <int C, int NL, bool PROJ>
__global__ __launch_bounds__(512, 2) void k23_kernel(
    const unsigned short* __restrict__ xbf, const unsigned short* __restrict__ Bsw,
    const float* __restrict__ biasWU, unsigned short* __restrict__ hbf,
    float* __restrict__ cbuf, int d0,
    const float* __restrict__ Wp, const float* __restrict__ bWp,
    float* __restrict__ out) {
    constexpr int TOTX = 2 * C - (C >> (NL - 1));
    constexpr int AR = (C < 16) ? 16 : C;
    __shared__ __align__(16) unsigned short xs[TOTX * XSTR];
    __shared__ __align__(16) unsigned short hA[AR * HSTR];
    __shared__ __align__(16) unsigned short hB[16 * HSTR];
    __shared__ __align__(16) float cA[AR * CSTR];
    __shared__ __align__(16) float cB[16 * CSTR];
    __shared__ float red[4][128];

    const int tid = threadIdx.x;
    const int w = tid >> 6, lane = tid & 63, L = lane & 15, q = lane >> 4;
    const int ch = w * 16 + L;

    short8 b[32];
#pragma unroll
    for (int t = 0; t < 32; ++t)
        b[t] = *(const short8*)(Bsw + ((size_t)w << 14) + (t << 9) + lane * 8);

    {
        int xoff = 0;
#pragma unroll
        for (int l = 0; l < NL; ++l) {
            const int rows = C >> l;
            const long base = ((1 << (d0 - l)) - 1) + (long)blockIdx.x * rows;
            for (int i = tid; i < rows * 16; i += 512) {
                const int row = i >> 4, g = i & 15;
                *(uint4*)(xs + (xoff + row) * XSTR + g * 8) =
                    *(const uint4*)(xbf + (size_t)(base + row) * DIM + g * 8);
            }
            xoff += rows;
        }
    }
    __syncthreads();

    const long cb = ((1 << (d0 + 1)) - 1) + (long)blockIdx.x * (2 * C);
    internal_level<true>(xs, nullptr, nullptr, hbf, cbuf, cb,
                         hA, HSTR, cA, CSTR, C, b, biasWU, L, q, ch);
    __syncthreads();

    const unsigned short* hin = hA;
    const float* cin = cA;
    int xoff = C;
#pragma unroll
    for (int l = 1; l < NL; ++l) {
        const int cnt = C >> l;
        if (!PROJ && l == NL - 1) {
            // root level: direct global store
            const long ob = ((1 << (d0 - (NL - 1))) - 1) + (long)blockIdx.x;
            internal_level<false>(xs + xoff * XSTR, hin, cin, nullptr, nullptr, 0,
                                  hbf + (size_t)ob * DIM, DIM,
                                  cbuf + (size_t)ob * DIM, DIM, cnt, b, biasWU, L, q, ch);
        } else {
            unsigned short* ho = (l & 1) ? hB : hA;
            float* co = (l & 1) ? cB : cA;
            internal_level<false>(xs + xoff * XSTR, hin, cin, nullptr, nullptr, 0,
                                  ho, HSTR, co, CSTR, cnt, b, biasWU, L, q, ch);
            __syncthreads();
            hin = ho; cin = co;
        }
        xoff += cnt;
    }

    if (PROJ) {
        const int o = tid & 127, sg = tid >> 7;
        float pacc = 0.f;
#pragma unroll
        for (int jj = 0; jj < 8; ++jj) {
            const int k = sg * 32 + jj * 4;
            float4 wv = *(const float4*)(Wp + o * DIM + k);
            pacc += bf2f(hin[k]) * wv.x + bf2f(hin[k + 1]) * wv.y +
                    bf2f(hin[k + 2]) * wv.z + bf2f(hin[k + 3]) * wv.w;
        }
        red[sg][o] = pacc;
        __syncthreads();
        if (tid < 128) out[tid] = bWp[tid] + red[0][tid] + red[1][tid] + red[2][tid] + red[3][tid];
    }
}

extern "C" void kernel_launch(void* const* d_in, const int* in_sizes, int n_in,
                              void* d_out, int out_size, void* d_ws, size_t ws_size,
                              hipStream_t stream) {
    const float* x   = (const float*)d_in[0];
    const float* Wi  = (const float*)d_in[2];  const float* bWi = (const float*)d_in[3];
    const float* Ui  = (const float*)d_in[4];  const float* bUi = (const float*)d_in[5];
    const float* Wf  = (const float*)d_in[6];  const float* bWf = (const float*)d_in[7];
    const float* Uf  = (const float*)d_in[8];  const float* bUf = (const float*)d_in[9];
    const float* Wo  = (const float*)d_in[10]; const float* bWo = (const float*)d_in[11];
    const float* Uo  = (const float*)d_in[12]; const float* bUo = (const float*)d_in[13];
    const float* Wu  = (const float*)d_in[14]; const float* bWu = (const float*)d_in[15];
    const float* Uu  = (const float*)d_in[16]; const float* bUu = (const float*)d_in[17];
    const float* Wp  = (const float*)d_in[18]; const float* bWp = (const float*)d_in[19];

    // ws: Bsw (131072 bf16) | biasWU(512 f32) | biasL(512 f32) |
    //     cbuf (4096*128 f32 = 2 MB) | hbf (4096*128 bf16 = 1 MB) |
    //     xbf (N*128 bf16 = 33.6 MB)
    unsigned short* Bsw = (unsigned short*)d_ws;
    float* biasWU = (float*)(Bsw + 131072);
    float* biasL  = biasWU + 512;
    float* cbuf   = biasL + 512;
    unsigned short* hbf = (unsigned short*)(cbuf + (size_t)4096 * DIM);
    unsigned short* xbf = hbf + (size_t)4096 * DIM;

    WPtrs p;
    p.W[0] = Wi; p.W[1] = Wo; p.W[2] = Wu; p.W[3] = Wf;
    p.U[0] = Ui; p.U[1] = Uo; p.U[2] = Uu; p.U[3] = Uf;
    p.bW[0] = bWi; p.bW[1] = bWo; p.bW[2] = bWu; p.bW[3] = bWf;
    p.bU[0] = bUi; p.bU[1] = bUo; p.bU[2] = bUu; p.bU[3] = bUf;

    prep_kernel<<<512, 256, 0, stream>>>(p, Bsw, biasWU, biasL);
    convx_kernel<<<4096, 256, 0, stream>>>(x, xbf, NTREE * 32);

    // K1: d16..d11, 2048 subtrees of 32 leaves, 256 persistent blocks.
    k1_kernel<<<256, 512, 0, stream>>>(xbf, Bsw, biasL, biasWU, hbf, cbuf);
    // K2: d10..d5, 32 subtree blocks (children = K1's d11 root rows).
    k23_kernel<32, 6, false><<<32, 512, 0, stream>>>(xbf, Bsw, biasWU, hbf, cbuf, 10,
                                                     nullptr, nullptr, nullptr);
    // K3: d4..d0 + projection (children = K2's d5 root rows).
    k23_kernel<16, 5, true><<<1, 512, 0, stream>>>(xbf, Bsw, biasWU, hbf, cbuf, 4,
                                                   Wp, bWp, (float*)d_out);
}

// Round 9
// 274.168 us; speedup vs baseline: 1.3035x; 1.3035x over previous
//
#include <hip/hip_runtime.h>
#include <hip/hip_bf16.h>

// ChildSumTreeLSTM, complete binary tree heap layout (children of n: 2n+1, 2n+2).
// R9: depth-2 fused ladder. kd2<LEAF>: 32 leaves + 16 d15 parents per block
// (2048 blocks); kd2<!LEAF>: 32 internal + 16 parents (d14+d13: 512 blocks,
// d12+d11: 128 blocks), level-0 children staged from global. k23 (proven)
// covers d10..d5 and d4..d0 + projection. Intra-block level-0 c passed as
// bf16 in LDS (f-gate damps the rounding); cross-kernel c fp32. B (wave's
// 16-col slice of all gates, K=256) register-resident: 32 short8 = 128 regs.
// XSTR=136 (272 B stride: 16B-aligned b128, 2-way banks = free). R8's
// register-prefetch (spilled to LDS) and XSTR=132 (misaligned) reverted.
// Bsw = fragment-stream-ordered [W/2 | U] (f-gate W unhalved), gates
// [i,o,u,f]; child row r computes [x_par; h_child]@B^T, epilogue sums row
// pairs in-lane. x pre-converted to bf16 once (convx).

#define DEPTH 17
#define NTREE ((1 << DEPTH) - 1)  // 131071
#define DIM 128
#define XSTR 136  // bf16 LDS row stride (shorts) = 272 B
#define HSTR 136
#define CSTR 132  // fp32 LDS row stride (floats) = 528 B

typedef __attribute__((ext_vector_type(8))) short short8;
typedef __attribute__((ext_vector_type(4))) float float4v;

__device__ __forceinline__ float sigm(float v) {
    return __fdividef(1.0f, 1.0f + __expf(-v));
}
__device__ __forceinline__ float ftanh(float v) {
    v = fminf(15.0f, fmaxf(-15.0f, v));
    float e = __expf(2.0f * v);
    return __fdividef(e - 1.0f, e + 1.0f);
}

__device__ __forceinline__ unsigned short f2bf(float f) {
    union { float f; unsigned u; } a; a.f = f;
    unsigned u = a.u;
    return (unsigned short)((u + 0x7fffu + ((u >> 16) & 1u)) >> 16);  // RNE
}
__device__ __forceinline__ float bf2f(unsigned short s) {
    union { unsigned u; float f; } a; a.u = ((unsigned)s) << 16;
    return a.f;
}

struct WPtrs {
    const float* W[4];  const float* U[4];
    const float* bW[4]; const float* bU[4];
};

// Bsw[w][ks][g][lane][j] (w:8, ks:8, g:4, lane:64, j:8) = fragment-stream order.
__global__ __launch_bounds__(256) void prep_kernel(WPtrs p, unsigned short* __restrict__ Bsw,
                                                   float* __restrict__ biasWU, float* __restrict__ biasL) {
    int idx = blockIdx.x * 256 + threadIdx.x;  // 0 .. 131071
    int j = idx & 7;
    int lane = (idx >> 3) & 63;
    int g = (idx >> 9) & 3;
    int ks = (idx >> 11) & 7;
    int w = idx >> 14;
    int L = lane & 15, q = lane >> 4;
    int c = w * 16 + L;
    int k = ks * 32 + q * 8 + j;
    float v = (k < 128) ? p.W[g][c * 128 + k] * (g == 3 ? 1.0f : 0.5f)
                        : p.U[g][c * 128 + (k - 128)];
    Bsw[idx] = f2bf(v);
    if (idx < 512) {
        int gg = idx >> 7, cc = idx & 127;
        biasWU[idx] = p.bW[gg][cc] + p.bU[gg][cc];
        biasL[idx]  = p.bW[gg][cc];
    }
}

__global__ __launch_bounds__(256) void convx_kernel(const float* __restrict__ x,
                                                    unsigned short* __restrict__ xbf, int n4) {
    int i = blockIdx.x * 256 + threadIdx.x;
    int stride = gridDim.x * 256;
    for (; i < n4; i += stride) {
        float4 v = ((const float4*)x)[i];
        ushort4 o;
        o.x = f2bf(v.x); o.y = f2bf(v.y); o.z = f2bf(v.z); o.w = f2bf(v.w);
        ((ushort4*)xbf)[i] = o;
    }
}

// ---------- depth-2 fused kernel: 32 level-0 nodes + 16 level-1 parents ----------
// LEAF0: level-0 = true leaves (K=128, gates i,o,u, logit=2*acc+bW).
// !LEAF0: level-0 = internal; child h staged from global, child c read global.
// Level-1: internal; children = level-0 (h bf16 LDS, c bf16 LDS).
// Output: level-1 h (bf16) + c (fp32) stored coalesced at heap rows n1..n1+15.
template <bool LEAF0>
__global__ __launch_bounds__(512, 2) void kd2_kernel(
    const unsigned short* __restrict__ xbf, const unsigned short* __restrict__ Bsw,
    const float* __restrict__ biasL, const float* __restrict__ biasWU,
    unsigned short* __restrict__ hbf, float* __restrict__ cbuf,
    int x0base, int x1base) {
    __shared__ __align__(16) unsigned short xs[48 * XSTR];
    __shared__ __align__(16) unsigned short hc[LEAF0 ? 16 : 64 * XSTR];  // child h (internal only)
    __shared__ __align__(16) unsigned short h0[32 * XSTR];  // level-0 h out (bf16)
    __shared__ __align__(16) unsigned short c0[32 * XSTR];  // level-0 c out (bf16)
    __shared__ __align__(16) unsigned short hA1[16 * XSTR]; // level-1 h assembly (bf16)
    __shared__ __align__(16) float cA1[16 * CSTR];          // level-1 c assembly (fp32)

    const int tid = threadIdx.x;
    const int w = tid >> 6, lane = tid & 63, L = lane & 15, q = lane >> 4;
    const int ch = w * 16 + L;

    short8 b[32];
#pragma unroll
    for (int t = 0; t < 32; ++t)
        b[t] = *(const short8*)(Bsw + ((size_t)w << 14) + (t << 9) + lane * 8);

    const long n0 = (long)x0base + (long)blockIdx.x * 32;  // level-0 heap base
    const long n1 = (long)x1base + (long)blockIdx.x * 16;  // level-1 heap base
    const long cb = 2 * n0 + 1;                            // level-0 children heap base

    // stage x: rows 0..31 = x[n0..], rows 32..47 = x[n1..]
    for (int i = tid; i < 48 * 16; i += 512) {
        const int row = i >> 4, g = i & 15;
        const long node = (row < 32) ? (n0 + row) : (n1 + (row - 32));
        *(uint4*)(xs + row * XSTR + g * 8) = *(const uint4*)(xbf + (size_t)node * DIM + g * 8);
    }
    if (!LEAF0) {  // stage 64 child h rows
        for (int i = tid; i < 64 * 16; i += 512) {
            const int row = i >> 4, g = i & 15;
            *(uint4*)(hc + row * XSTR + g * 8) = *(const uint4*)(hbf + (size_t)(cb + row) * DIM + g * 8);
        }
    }
    __syncthreads();

    // ---- level 0: 32 nodes ----
    if (LEAF0) {
        float4v acc[2][3];
#pragma unroll
        for (int mm = 0; mm < 2; ++mm)
#pragma unroll
            for (int g = 0; g < 3; ++g) acc[mm][g] = (float4v){0.f, 0.f, 0.f, 0.f};
#pragma unroll
        for (int ks = 0; ks < 4; ++ks) {
            short8 a[2];
            a[0] = *(const short8*)(xs + L * XSTR + ks * 32 + q * 8);
            a[1] = *(const short8*)(xs + (16 + L) * XSTR + ks * 32 + q * 8);
#pragma unroll
            for (int g = 0; g < 3; ++g)
#pragma unroll
                for (int mm = 0; mm < 2; ++mm)
                    acc[mm][g] = __builtin_amdgcn_mfma_f32_16x16x32_bf16(a[mm], b[ks * 4 + g], acc[mm][g], 0, 0, 0);
        }
#pragma unroll
        for (int mm = 0; mm < 2; ++mm)
#pragma unroll
            for (int r = 0; r < 4; ++r) {
                const int nl = 16 * mm + q * 4 + r;
                float iv = sigm(2.f * acc[mm][0][r] + biasL[ch]);
                float ov = sigm(2.f * acc[mm][1][r] + biasL[128 + ch]);
                float uv = ftanh(2.f * acc[mm][2][r] + biasL[256 + ch]);
                float cv = iv * uv;
                c0[nl * XSTR + ch] = f2bf(cv);
                h0[nl * XSTR + ch] = f2bf(ov * ftanh(cv));
            }
    } else {
        for (int mc = 0; mc < 4; mc += 2) {
            float4v acc[2][4];
#pragma unroll
            for (int mm = 0; mm < 2; ++mm)
#pragma unroll
                for (int g = 0; g < 4; ++g) acc[mm][g] = (float4v){0.f, 0.f, 0.f, 0.f};
#pragma unroll
            for (int ks = 0; ks < 8; ++ks) {
                const int kk = ks * 32;
                short8 a[2];
#pragma unroll
                for (int mm = 0; mm < 2; ++mm) {
                    if (kk < 128)
                        a[mm] = *(const short8*)(xs + (8 * (mc + mm) + (L >> 1)) * XSTR + kk + q * 8);
                    else
                        a[mm] = *(const short8*)(hc + (16 * (mc + mm) + L) * XSTR + (kk - 128) + q * 8);
                }
#pragma unroll
                for (int g = 0; g < 4; ++g)
#pragma unroll
                    for (int mm = 0; mm < 2; ++mm)
                        acc[mm][g] = __builtin_amdgcn_mfma_f32_16x16x32_bf16(a[mm], b[ks * 4 + g], acc[mm][g], 0, 0, 0);
            }
#pragma unroll
            for (int mm = 0; mm < 2; ++mm)
#pragma unroll
                for (int e = 0; e < 2; ++e) {
                    const int nl = 8 * (mc + mm) + 2 * q + e;
                    const int r0 = 2 * e, r1 = 2 * e + 1;
                    float iv = sigm(acc[mm][0][r0] + acc[mm][0][r1] + biasWU[ch]);
                    float ov = sigm(acc[mm][1][r0] + acc[mm][1][r1] + biasWU[128 + ch]);
                    float uv = ftanh(acc[mm][2][r0] + acc[mm][2][r1] + biasWU[256 + ch]);
                    float fl = sigm(acc[mm][3][r0] + biasWU[384 + ch]);
                    float fr = sigm(acc[mm][3][r1] + biasWU[384 + ch]);
                    float cl = cbuf[(size_t)(cb + 2 * nl) * DIM + ch];
                    float cr = cbuf[(size_t)(cb + 2 * nl + 1) * DIM + ch];
                    float cv = iv * uv + fl * cl + fr * cr;
                    c0[nl * XSTR + ch] = f2bf(cv);
                    h0[nl * XSTR + ch] = f2bf(ov * ftanh(cv));
                }
        }
    }
    __syncthreads();

    // ---- level 1: 16 parents (children = level-0 in LDS) ----
    {
        float4v acc[2][4];
#pragma unroll
        for (int mm = 0; mm < 2; ++mm)
#pragma unroll
            for (int g = 0; g < 4; ++g) acc[mm][g] = (float4v){0.f, 0.f, 0.f, 0.f};
#pragma unroll
        for (int ks = 0; ks < 8; ++ks) {
            const int kk = ks * 32;
            short8 a[2];
#pragma unroll
            for (int mm = 0; mm < 2; ++mm) {
                if (kk < 128)
                    a[mm] = *(const short8*)(xs + (32 + 8 * mm + (L >> 1)) * XSTR + kk + q * 8);
                else
                    a[mm] = *(const short8*)(h0 + (16 * mm + L) * XSTR + (kk - 128) + q * 8);
            }
#pragma unroll
            for (int g = 0; g < 4; ++g)
#pragma unroll
                for (int mm = 0; mm < 2; ++mm)
                    acc[mm][g] = __builtin_amdgcn_mfma_f32_16x16x32_bf16(a[mm], b[ks * 4 + g], acc[mm][g], 0, 0, 0);
        }
#pragma unroll
        for (int mm = 0; mm < 2; ++mm)
#pragma unroll
            for (int e = 0; e < 2; ++e) {
                const int nl = 8 * mm + 2 * q + e;
                const int r0 = 2 * e, r1 = 2 * e + 1;
                float iv = sigm(acc[mm][0][r0] + acc[mm][0][r1] + biasWU[ch]);
                float ov = sigm(acc[mm][1][r0] + acc[mm][1][r1] + biasWU[128 + ch]);
                float uv = ftanh(acc[mm][2][r0] + acc[mm][2][r1] + biasWU[256 + ch]);
                float fl = sigm(acc[mm][3][r0] + biasWU[384 + ch]);
                float fr = sigm(acc[mm][3][r1] + biasWU[384 + ch]);
                float cl = bf2f(c0[(2 * nl) * XSTR + ch]);
                float cr = bf2f(c0[(2 * nl + 1) * XSTR + ch]);
                float cv = iv * uv + fl * cl + fr * cr;
                cA1[nl * CSTR + ch] = cv;
                hA1[nl * XSTR + ch] = f2bf(ov * ftanh(cv));
            }
    }
    __syncthreads();

    // coalesced store of the 16 level-1 rows
    for (int i = tid; i < 16 * 16; i += 512) {
        const int row = i >> 4, g = i & 15;
        *(uint4*)(hbf + (size_t)(n1 + row) * DIM + g * 8) = *(const uint4*)(hA1 + row * XSTR + g * 8);
    }
    for (int i = tid; i < 16 * 32; i += 512) {
        const int row = i >> 5, j = i & 31;
        *(float4*)(cbuf + (size_t)(n1 + row) * DIM + j * 4) = *(const float4*)(cA1 + row * CSTR + j * 4);
    }
}

// ---------- k23: fused multi-level subtree (proven in R7/R8, strides fixed) ----------
template <bool GCH>
__device__ __forceinline__ void internal_level(
    const unsigned short* xc,
    const unsigned short* hin_l, const float* cin_l,
    const unsigned short* __restrict__ hin_g, const float* __restrict__ cin_g, long cb,
    unsigned short* ho, int ho_str, float* co, int co_str, int cnt,
    const short8 (&b)[32], const float* __restrict__ biasWU,
    int L, int q, int ch) {
    const int rows = 2 * cnt;
    const int mt = (rows + 15) >> 4;
    for (int mc = 0; mc < mt; mc += 2) {
        const int mm_n = (mt - mc >= 2) ? 2 : 1;
        float4v acc[2][4];
#pragma unroll
        for (int mm = 0; mm < 2; ++mm)
#pragma unroll
            for (int g = 0; g < 4; ++g) acc[mm][g] = (float4v){0.f, 0.f, 0.f, 0.f};
#pragma unroll
        for (int ks = 0; ks < 8; ++ks) {
            const int kk = ks * 32;
            short8 a[2];
#pragma unroll
            for (int mm = 0; mm < 2; ++mm) {
                if (mm < mm_n) {
                    if (kk < 128) {
                        int xr = 8 * (mc + mm) + (L >> 1);
                        if (xr >= cnt) xr = 0;
                        a[mm] = *(const short8*)(xc + xr * XSTR + kk + q * 8);
                    } else if (!GCH) {
                        a[mm] = *(const short8*)(hin_l + (16 * (mc + mm) + L) * HSTR + (kk - 128) + q * 8);
                    } else {
                        a[mm] = *(const short8*)(hin_g + (size_t)(cb + 16 * (mc + mm) + L) * DIM + (kk - 128) + q * 8);
                    }
                }
            }
#pragma unroll
            for (int g = 0; g < 4; ++g)
#pragma unroll
                for (int mm = 0; mm < 2; ++mm)
                    if (mm < mm_n)
                        acc[mm][g] = __builtin_amdgcn_mfma_f32_16x16x32_bf16(a[mm], b[ks * 4 + g], acc[mm][g], 0, 0, 0);
        }
#pragma unroll
        for (int mm = 0; mm < 2; ++mm)
#pragma unroll
            for (int e = 0; e < 2; ++e) {
                if (mm < mm_n) {
                    const int nl = 8 * (mc + mm) + 2 * q + e;
                    if (nl < cnt) {
                        const int r0 = 2 * e, r1 = 2 * e + 1;
                        float iv = sigm(acc[mm][0][r0] + acc[mm][0][r1] + biasWU[ch]);
                        float ov = sigm(acc[mm][1][r0] + acc[mm][1][r1] + biasWU[128 + ch]);
                        float uv = ftanh(acc[mm][2][r0] + acc[mm][2][r1] + biasWU[256 + ch]);
                        float fl = sigm(acc[mm][3][r0] + biasWU[384 + ch]);
                        float fr = sigm(acc[mm][3][r1] + biasWU[384 + ch]);
                        float cl, cr;
                        if (!GCH) {
                            cl = cin_l[(2 * nl) * CSTR + ch];
                            cr = cin_l[(2 * nl + 1) * CSTR + ch];
                        } else {
                            cl = cin_g[(size_t)(cb + 2 * nl) * DIM + ch];
                            cr = cin_g[(size_t)(cb + 2 * nl + 1) * DIM + ch];
                        }
                        float cv = iv * uv + fl * cl + fr * cr;
                        co[nl * co_str + ch] = cv;
                        ho[nl * ho_str + ch] = f2bf(ov * ftanh(cv));
                    }
                }
            }
    }
}

// K2/K3: level-0 children from global rows [cb, cb+2C).
// K2: C=32, NL=6, d0=10 (32 blocks, root -> global). K3: C=16, NL=5, d0=4, PROJ.
template <int C, int NL, bool PROJ>
__global__ __launch_bounds__(512, 2) void k23_kernel(
    const unsigned short* __restrict__ xbf, const unsigned short* __restrict__ Bsw,
    const float* __restrict__ biasWU, unsigned short* __restrict__ hbf,
    float* __restrict__ cbuf, int d0,
    const float* __restrict__ Wp, const float* __restrict__ bWp,
    float* __restrict__ out) {
    constexpr int TOTX = 2 * C - (C >> (NL - 1));
    constexpr int AR = (C < 16) ? 16 : C;
    __shared__ __align__(16) unsigned short xs[TOTX * XSTR];
    __shared__ __align__(16) unsigned short hA[AR * HSTR];
    __shared__ __align__(16) unsigned short hB[16 * HSTR];
    __shared__ __align__(16) float cA[AR * CSTR];
    __shared__ __align__(16) float cB[16 * CSTR];
    __shared__ float red[4][128];

    const int tid = threadIdx.x;
    const int w = tid >> 6, lane = tid & 63, L = lane & 15, q = lane >> 4;
    const int ch = w * 16 + L;

    short8 b[32];
#pragma unroll
    for (int t = 0; t < 32; ++t)
        b[t] = *(const short8*)(Bsw + ((size_t)w << 14) + (t << 9) + lane * 8);

    {
        int xoff = 0;
#pragma unroll
        for (int l = 0; l < NL; ++l) {
            const int rows = C >> l;
            const long base = ((1 << (d0 - l)) - 1) + (long)blockIdx.x * rows;
            for (int i = tid; i < rows * 16; i += 512) {
                const int row = i >> 4, g = i & 15;
                *(uint4*)(xs + (xoff + row) * XSTR + g * 8) =
                    *(const uint4*)(xbf + (size_t)(base + row) * DIM + g * 8);
            }
            xoff += rows;
        }
    }
    __syncthreads();

    const long cb = ((1 << (d0 + 1)) - 1) + (long)blockIdx.x * (2 * C);
    internal_level<true>(xs, nullptr, nullptr, hbf, cbuf, cb,
                         hA, HSTR, cA, CSTR, C, b, biasWU, L, q, ch);
    __syncthreads();

    const unsigned short* hin = hA;
    const float* cin = cA;
    int xoff = C;
#pragma unroll
    for (int l = 1; l < NL; ++l) {
        const int cnt = C >> l;
        if (!PROJ && l == NL - 1) {
            const long ob = ((1 << (d0 - (NL - 1))) - 1) + (long)blockIdx.x;
            internal_level<false>(xs + xoff * XSTR, hin, cin, nullptr, nullptr, 0,
                                  hbf + (size_t)ob * DIM, DIM,
                                  cbuf + (size_t)ob * DIM, DIM, cnt, b, biasWU, L, q, ch);
        } else {
            unsigned short* ho = (l & 1) ? hB : hA;
            float* co = (l & 1) ? cB : cA;
            internal_level<false>(xs + xoff * XSTR, hin, cin, nullptr, nullptr, 0,
                                  ho, HSTR, co, CSTR, cnt, b, biasWU, L, q, ch);
            __syncthreads();
            hin = ho; cin = co;
        }
        xoff += cnt;
    }

    if (PROJ) {
        const int o = tid & 127, sg = tid >> 7;
        float pacc = 0.f;
#pragma unroll
        for (int jj = 0; jj < 8; ++jj) {
            const int k = sg * 32 + jj * 4;
            float4 wv = *(const float4*)(Wp + o * DIM + k);
            pacc += bf2f(hin[k]) * wv.x + bf2f(hin[k + 1]) * wv.y +
                    bf2f(hin[k + 2]) * wv.z + bf2f(hin[k + 3]) * wv.w;
        }
        red[sg][o] = pacc;
        __syncthreads();
        if (tid < 128) out[tid] = bWp[tid] + red[0][tid] + red[1][tid] + red[2][tid] + red[3][tid];
    }
}

extern "C" void kernel_launch(void* const* d_in, const int* in_sizes, int n_in,
                              void* d_out, int out_size, void* d_ws, size_t ws_size,
                              hipStream_t stream) {
    const float* x   = (const float*)d_in[0];
    const float* Wi  = (const float*)d_in[2];  const float* bWi = (const float*)d_in[3];
    const float* Ui  = (const float*)d_in[4];  const float* bUi = (const float*)d_in[5];
    const float* Wf  = (const float*)d_in[6];  const float* bWf = (const float*)d_in[7];
    const float* Uf  = (const float*)d_in[8];  const float* bUf = (const float*)d_in[9];
    const float* Wo  = (const float*)d_in[10]; const float* bWo = (const float*)d_in[11];
    const float* Uo  = (const float*)d_in[12]; const float* bUo = (const float*)d_in[13];
    const float* Wu  = (const float*)d_in[14]; const float* bWu = (const float*)d_in[15];
    const float* Uu  = (const float*)d_in[16]; const float* bUu = (const float*)d_in[17];
    const float* Wp  = (const float*)d_in[18]; const float* bWp = (const float*)d_in[19];

    // ws: Bsw (131072 bf16) | biasWU(512 f32) | biasL(512 f32) |
    //     cbuf (65536*128 f32 = 33.6 MB) | hbf (65536*128 bf16 = 16.8 MB) |
    //     xbf (N*128 bf16 = 33.6 MB)
    unsigned short* Bsw = (unsigned short*)d_ws;
    float* biasWU = (float*)(Bsw + 131072);
    float* biasL  = biasWU + 512;
    float* cbuf   = biasL + 512;
    unsigned short* hbf = (unsigned short*)(cbuf + (size_t)65536 * DIM);
    unsigned short* xbf = hbf + (size_t)65536 * DIM;

    WPtrs p;
    p.W[0] = Wi; p.W[1] = Wo; p.W[2] = Wu; p.W[3] = Wf;
    p.U[0] = Ui; p.U[1] = Uo; p.U[2] = Uu; p.U[3] = Uf;
    p.bW[0] = bWi; p.bW[1] = bWo; p.bW[2] = bWu; p.bW[3] = bWf;
    p.bU[0] = bUi; p.bU[1] = bUo; p.bU[2] = bUu; p.bU[3] = bUf;

    prep_kernel<<<512, 256, 0, stream>>>(p, Bsw, biasWU, biasL);
    convx_kernel<<<4096, 256, 0, stream>>>(x, xbf, NTREE * 32);

    // K_A: d16 (leaves) + d15 -> writes d15 rows. 65536/32 = 2048 blocks.
    kd2_kernel<true><<<2048, 512, 0, stream>>>(xbf, Bsw, biasL, biasWU, hbf, cbuf,
                                               (1 << 16) - 1, (1 << 15) - 1);
    // K_B: d14 + d13 (children = d15 global) -> writes d13. 16384/32 = 512 blocks.
    kd2_kernel<false><<<512, 512, 0, stream>>>(xbf, Bsw, biasL, biasWU, hbf, cbuf,
                                               (1 << 14) - 1, (1 << 13) - 1);
    // K_C: d12 + d11 (children = d13 global) -> writes d11. 4096/32 = 128 blocks.
    kd2_kernel<false><<<128, 512, 0, stream>>>(xbf, Bsw, biasL, biasWU, hbf, cbuf,
                                               (1 << 12) - 1, (1 << 11) - 1);
    // K_D: d10..d5 (children = d11 global), 32 blocks.
    k23_kernel<32, 6, false><<<32, 512, 0, stream>>>(xbf, Bsw, biasWU, hbf, cbuf, 10,
                                                     nullptr, nullptr, nullptr);
    // K_E: d4..d0 + projection (children = d5 global).
    k23_kernel<16, 5, true><<<1, 512, 0, stream>>>(xbf, Bsw, biasWU, hbf, cbuf, 4,
                                                   Wp, bWp, (float*)d_out);
}

// Round 10
// 243.971 us; speedup vs baseline: 1.4649x; 1.1238x over previous
//
#include <hip/hip_runtime.h>
#include <hip/hip_bf16.h>

// ChildSumTreeLSTM, complete binary tree heap layout (children of n: 2n+1, 2n+2).
// R10: persistent depth-2 ladder. kd2p: grid=256 (1 block/CU), each block loops
// over its tiles (32 level-0 nodes + 16 level-1 parents per tile); B register-
// resident loaded ONCE; next tile's x prefetched into 12 VGPRs (published at
// loop top -- single xs buffer is safe: last xs read precedes barrier B3).
// x read as fp32 directly (convx deleted). k23 covers d10..d5 and d4..d0+proj.
// Intra-block level-0 c passed bf16 through LDS; cross-kernel c fp32.
// Bsw = fragment-stream-ordered [W/2 | U] (f-gate W unhalved), gates [i,o,u,f];
// child row r computes [x_par; h_child]@B^T, epilogue sums row pairs in-lane.

#define DEPTH 17
#define NTREE ((1 << DEPTH) - 1)  // 131071
#define DIM 128
#define XSTR 136  // bf16 LDS row stride (shorts) = 272 B (16B-aligned, 2-way banks = free)
#define HSTR 136
#define CSTR 132  // fp32 LDS row stride (floats)

typedef __attribute__((ext_vector_type(8))) short short8;
typedef __attribute__((ext_vector_type(4))) float float4v;

__device__ __forceinline__ float sigm(float v) {
    return __fdividef(1.0f, 1.0f + __expf(-v));
}
__device__ __forceinline__ float ftanh(float v) {
    v = fminf(15.0f, fmaxf(-15.0f, v));
    float e = __expf(2.0f * v);
    return __fdividef(e - 1.0f, e + 1.0f);
}

__device__ __forceinline__ unsigned short f2bf(float f) {
    union { float f; unsigned u; } a; a.f = f;
    unsigned u = a.u;
    return (unsigned short)((u + 0x7fffu + ((u >> 16) & 1u)) >> 16);  // RNE
}
__device__ __forceinline__ float bf2f(unsigned short s) {
    union { unsigned u; float f; } a; a.u = ((unsigned)s) << 16;
    return a.f;
}

struct WPtrs {
    const float* W[4];  const float* U[4];
    const float* bW[4]; const float* bU[4];
};

// Bsw[w][ks][g][lane][j] (w:8, ks:8, g:4, lane:64, j:8) = fragment-stream order.
__global__ __launch_bounds__(256) void prep_kernel(WPtrs p, unsigned short* __restrict__ Bsw,
                                                   float* __restrict__ biasWU, float* __restrict__ biasL) {
    int idx = blockIdx.x * 256 + threadIdx.x;  // 0 .. 131071
    int j = idx & 7;
    int lane = (idx >> 3) & 63;
    int g = (idx >> 9) & 3;
    int ks = (idx >> 11) & 7;
    int w = idx >> 14;
    int L = lane & 15, q = lane >> 4;
    int c = w * 16 + L;
    int k = ks * 32 + q * 8 + j;
    float v = (k < 128) ? p.W[g][c * 128 + k] * (g == 3 ? 1.0f : 0.5f)
                        : p.U[g][c * 128 + (k - 128)];
    Bsw[idx] = f2bf(v);
    if (idx < 512) {
        int gg = idx >> 7, cc = idx & 127;
        biasWU[idx] = p.bW[gg][cc] + p.bU[gg][cc];
        biasL[idx]  = p.bW[gg][cc];
    }
}

// ---------- persistent depth-2 kernel ----------
// Tile = 32 level-0 nodes (at x0base + tt*32) + 16 level-1 parents (x1base + tt*16).
// LEAF0: level-0 = true leaves (K=128, gates i,o,u, logit=2*acc+bW).
template <bool LEAF0>
__global__ __launch_bounds__(512, 2) void kd2p_kernel(
    const float* __restrict__ x, const unsigned short* __restrict__ Bsw,
    const float* __restrict__ biasL, const float* __restrict__ biasWU,
    unsigned short* __restrict__ hbf, float* __restrict__ cbuf,
    int x0base, int x1base, int ntiles) {
    __shared__ __align__(16) unsigned short xs[48 * XSTR];
    __shared__ __align__(16) unsigned short hc[LEAF0 ? 16 : 64 * XSTR];
    __shared__ __align__(16) unsigned short h0[32 * XSTR];
    __shared__ __align__(16) unsigned short c0[32 * XSTR];
    __shared__ __align__(16) unsigned short hA1[16 * XSTR];
    __shared__ __align__(16) float cA1[16 * CSTR];

    const int tid = threadIdx.x;
    const int w = tid >> 6, lane = tid & 63, L = lane & 15, q = lane >> 4;
    const int ch = w * 16 + L;

    short8 b[32];
#pragma unroll
    for (int t = 0; t < 32; ++t)
        b[t] = *(const short8*)(Bsw + ((size_t)w << 14) + (t << 9) + lane * 8);

    // x prefetch regs: 48 rows * 32 float4 = 1536 granules = 3/thread
    float4 pfx[3];
    {
        const long tt = blockIdx.x;
        const long n0 = (long)x0base + tt * 32, n1 = (long)x1base + tt * 16;
#pragma unroll
        for (int k = 0; k < 3; ++k) {
            const int i = tid + 512 * k;
            const int row = i >> 5, j = i & 31;
            const long node = (row < 32) ? (n0 + row) : (n1 + (row - 32));
            pfx[k] = *(const float4*)(x + (size_t)node * DIM + j * 4);
        }
    }

    for (int it = 0; it < ntiles; ++it) {
        const long tt = (long)it * gridDim.x + blockIdx.x;
        const long n0 = (long)x0base + tt * 32;
        const long n1 = (long)x1base + tt * 16;
        const long cb = 2 * n0 + 1;

        // publish prefetched x (converted to bf16)
#pragma unroll
        for (int k = 0; k < 3; ++k) {
            const int i = tid + 512 * k;
            const int row = i >> 5, j = i & 31;
            ushort4 o;
            o.x = f2bf(pfx[k].x); o.y = f2bf(pfx[k].y);
            o.z = f2bf(pfx[k].z); o.w = f2bf(pfx[k].w);
            *(ushort4*)(xs + row * XSTR + j * 4) = o;
        }
        if (!LEAF0) {  // stage 64 child h rows (previous dispatch's output)
            for (int i = tid; i < 64 * 16; i += 512) {
                const int row = i >> 4, g = i & 15;
                *(uint4*)(hc + row * XSTR + g * 8) =
                    *(const uint4*)(hbf + (size_t)(cb + row) * DIM + g * 8);
            }
        }
        __syncthreads();  // B1

        // issue next tile's x prefetch (in flight across L0+L1 compute)
        if (it + 1 < ntiles) {
            const long tn = tt + gridDim.x;
            const long m0 = (long)x0base + tn * 32, m1 = (long)x1base + tn * 16;
#pragma unroll
            for (int k = 0; k < 3; ++k) {
                const int i = tid + 512 * k;
                const int row = i >> 5, j = i & 31;
                const long node = (row < 32) ? (m0 + row) : (m1 + (row - 32));
                pfx[k] = *(const float4*)(x + (size_t)node * DIM + j * 4);
            }
        }

        // ---- level 0: 32 nodes ----
        if (LEAF0) {
            float4v acc[2][3];
#pragma unroll
            for (int mm = 0; mm < 2; ++mm)
#pragma unroll
                for (int g = 0; g < 3; ++g) acc[mm][g] = (float4v){0.f, 0.f, 0.f, 0.f};
#pragma unroll
            for (int ks = 0; ks < 4; ++ks) {
                short8 a[2];
                a[0] = *(const short8*)(xs + L * XSTR + ks * 32 + q * 8);
                a[1] = *(const short8*)(xs + (16 + L) * XSTR + ks * 32 + q * 8);
#pragma unroll
                for (int g = 0; g < 3; ++g)
#pragma unroll
                    for (int mm = 0; mm < 2; ++mm)
                        acc[mm][g] = __builtin_amdgcn_mfma_f32_16x16x32_bf16(a[mm], b[ks * 4 + g], acc[mm][g], 0, 0, 0);
            }
#pragma unroll
            for (int mm = 0; mm < 2; ++mm)
#pragma unroll
                for (int r = 0; r < 4; ++r) {
                    const int nl = 16 * mm + q * 4 + r;
                    float iv = sigm(2.f * acc[mm][0][r] + biasL[ch]);
                    float ov = sigm(2.f * acc[mm][1][r] + biasL[128 + ch]);
                    float uv = ftanh(2.f * acc[mm][2][r] + biasL[256 + ch]);
                    float cv = iv * uv;
                    c0[nl * XSTR + ch] = f2bf(cv);
                    h0[nl * XSTR + ch] = f2bf(ov * ftanh(cv));
                }
        } else {
            for (int mc = 0; mc < 4; mc += 2) {
                float4v acc[2][4];
#pragma unroll
                for (int mm = 0; mm < 2; ++mm)
#pragma unroll
                    for (int g = 0; g < 4; ++g) acc[mm][g] = (float4v){0.f, 0.f, 0.f, 0.f};
#pragma unroll
                for (int ks = 0; ks < 8; ++ks) {
                    const int kk = ks * 32;
                    short8 a[2];
#pragma unroll
                    for (int mm = 0; mm < 2; ++mm) {
                        if (kk < 128)
                            a[mm] = *(const short8*)(xs + (8 * (mc + mm) + (L >> 1)) * XSTR + kk + q * 8);
                        else
                            a[mm] = *(const short8*)(hc + (16 * (mc + mm) + L) * XSTR + (kk - 128) + q * 8);
                    }
#pragma unroll
                    for (int g = 0; g < 4; ++g)
#pragma unroll
                        for (int mm = 0; mm < 2; ++mm)
                            acc[mm][g] = __builtin_amdgcn_mfma_f32_16x16x32_bf16(a[mm], b[ks * 4 + g], acc[mm][g], 0, 0, 0);
                }
#pragma unroll
                for (int mm = 0; mm < 2; ++mm)
#pragma unroll
                    for (int e = 0; e < 2; ++e) {
                        const int nl = 8 * (mc + mm) + 2 * q + e;
                        const int r0 = 2 * e, r1 = 2 * e + 1;
                        float iv = sigm(acc[mm][0][r0] + acc[mm][0][r1] + biasWU[ch]);
                        float ov = sigm(acc[mm][1][r0] + acc[mm][1][r1] + biasWU[128 + ch]);
                        float uv = ftanh(acc[mm][2][r0] + acc[mm][2][r1] + biasWU[256 + ch]);
                        float fl = sigm(acc[mm][3][r0] + biasWU[384 + ch]);
                        float fr = sigm(acc[mm][3][r1] + biasWU[384 + ch]);
                        float cl = cbuf[(size_t)(cb + 2 * nl) * DIM + ch];
                        float cr = cbuf[(size_t)(cb + 2 * nl + 1) * DIM + ch];
                        float cv = iv * uv + fl * cl + fr * cr;
                        c0[nl * XSTR + ch] = f2bf(cv);
                        h0[nl * XSTR + ch] = f2bf(ov * ftanh(cv));
                    }
            }
        }
        __syncthreads();  // B2

        // ---- level 1: 16 parents (children = level-0 in LDS) ----
        {
            float4v acc[2][4];
#pragma unroll
            for (int mm = 0; mm < 2; ++mm)
#pragma unroll
                for (int g = 0; g < 4; ++g) acc[mm][g] = (float4v){0.f, 0.f, 0.f, 0.f};
#pragma unroll
            for (int ks = 0; ks < 8; ++ks) {
                const int kk = ks * 32;
                short8 a[2];
#pragma unroll
                for (int mm = 0; mm < 2; ++mm) {
                    if (kk < 128)
                        a[mm] = *(const short8*)(xs + (32 + 8 * mm + (L >> 1)) * XSTR + kk + q * 8);
                    else
                        a[mm] = *(const short8*)(h0 + (16 * mm + L) * XSTR + (kk - 128) + q * 8);
                }
#pragma unroll
                for (int g = 0; g < 4; ++g)
#pragma unroll
                    for (int mm = 0; mm < 2; ++mm)
                        acc[mm][g] = __builtin_amdgcn_mfma_f32_16x16x32_bf16(a[mm], b[ks * 4 + g], acc[mm][g], 0, 0, 0);
            }
#pragma unroll
            for (int mm = 0; mm < 2; ++mm)
#pragma unroll
                for (int e = 0; e < 2; ++e) {
                    const int nl = 8 * mm + 2 * q + e;
                    const int r0 = 2 * e, r1 = 2 * e + 1;
                    float iv = sigm(acc[mm][0][r0] + acc[mm][0][r1] + biasWU[ch]);
                    float ov = sigm(acc[mm][1][r0] + acc[mm][1][r1] + biasWU[128 + ch]);
                    float uv = ftanh(acc[mm][2][r0] + acc[mm][2][r1] + biasWU[256 + ch]);
                    float fl = sigm(acc[mm][3][r0] + biasWU[384 + ch]);
                    float fr = sigm(acc[mm][3][r1] + biasWU[384 + ch]);
                    float cl = bf2f(c0[(2 * nl) * XSTR + ch]);
                    float cr = bf2f(c0[(2 * nl + 1) * XSTR + ch]);
                    float cv = iv * uv + fl * cl + fr * cr;
                    cA1[nl * CSTR + ch] = cv;
                    hA1[nl * XSTR + ch] = f2bf(ov * ftanh(cv));
                }
        }
        __syncthreads();  // B3

        // coalesced store of the 16 level-1 rows (hA1/cA1 are the only reads here,
        // so the next iteration's xs/hc publish needs no extra barrier)
        for (int i = tid; i < 16 * 16; i += 512) {
            const int row = i >> 4, g = i & 15;
            *(uint4*)(hbf + (size_t)(n1 + row) * DIM + g * 8) = *(const uint4*)(hA1 + row * XSTR + g * 8);
        }
        for (int i = tid; i < 16 * 32; i += 512) {
            const int row = i >> 5, j = i & 31;
            *(float4*)(cbuf + (size_t)(n1 + row) * DIM + j * 4) = *(const float4*)(cA1 + row * CSTR + j * 4);
        }
    }
}

// ---------- k23: fused multi-level subtree (fp32 x staging) ----------
template <bool GCH>
__device__ __forceinline__ void internal_level(
    const unsigned short* xc,
    const unsigned short* hin_l, const float* cin_l,
    const unsigned short* __restrict__ hin_g, const float* __restrict__ cin_g, long cb,
    unsigned short* ho, int ho_str, float* co, int co_str, int cnt,
    const short8 (&b)[32], const float* __restrict__ biasWU,
    int L, int q, int ch) {
    const int rows = 2 * cnt;
    const int mt = (rows + 15) >> 4;
    for (int mc = 0; mc < mt; mc += 2) {
        const int mm_n = (mt - mc >= 2) ? 2 : 1;
        float4v acc[2][4];
#pragma unroll
        for (int mm = 0; mm < 2; ++mm)
#pragma unroll
            for (int g = 0; g < 4; ++g) acc[mm][g] = (float4v){0.f, 0.f, 0.f, 0.f};
#pragma unroll
        for (int ks = 0; ks < 8; ++ks) {
            const int kk = ks * 32;
            short8 a[2];
#pragma unroll
            for (int mm = 0; mm < 2; ++mm) {
                if (mm < mm_n) {
                    if (kk < 128) {
                        int xr = 8 * (mc + mm) + (L >> 1);
                        if (xr >= cnt) xr = 0;
                        a[mm] = *(const short8*)(xc + xr * XSTR + kk + q * 8);
                    } else if (!GCH) {
                        a[mm] = *(const short8*)(hin_l + (16 * (mc + mm) + L) * HSTR + (kk - 128) + q * 8);
                    } else {
                        a[mm] = *(const short8*)(hin_g + (size_t)(cb + 16 * (mc + mm) + L) * DIM + (kk - 128) + q * 8);
                    }
                }
            }
#pragma unroll
            for (int g = 0; g < 4; ++g)
#pragma unroll
                for (int mm = 0; mm < 2; ++mm)
                    if (mm < mm_n)
                        acc[mm][g] = __builtin_amdgcn_mfma_f32_16x16x32_bf16(a[mm], b[ks * 4 + g], acc[mm][g], 0, 0, 0);
        }
#pragma unroll
        for (int mm = 0; mm < 2; ++mm)
#pragma unroll
            for (int e = 0; e < 2; ++e) {
                if (mm < mm_n) {
                    const int nl = 8 * (mc + mm) + 2 * q + e;
                    if (nl < cnt) {
                        const int r0 = 2 * e, r1 = 2 * e + 1;
                        float iv = sigm(acc[mm][0][r0] + acc[mm][0][r1] + biasWU[ch]);
                        float ov = sigm(acc[mm][1][r0] + acc[mm][1][r1] + biasWU[128 + ch]);
                        float uv = ftanh(acc[mm][2][r0] + acc[mm][2][r1] + biasWU[256 + ch]);
                        float fl = sigm(acc[mm][3][r0] + biasWU[384 + ch]);
                        float fr = sigm(acc[mm][3][r1] + biasWU[384 + ch]);
                        float cl, cr;
                        if (!GCH) {
                            cl = cin_l[(2 * nl) * CSTR + ch];
                            cr = cin_l[(2 * nl + 1) * CSTR + ch];
                        } else {
                            cl = cin_g[(size_t)(cb + 2 * nl) * DIM + ch];
                            cr = cin_g[(size_t)(cb + 2 * nl + 1) * DIM + ch];
                        }
                        float cv = iv * uv + fl * cl + fr * cr;
                        co[nl * co_str + ch] = cv;
                        ho[nl * ho_str + ch] = f2bf(ov * ftanh(cv));
                    }
                }
            }
    }
}

// K_D: C=32, NL=6, d0=10 (32 blocks, root -> global). K_E: C=16, NL=5, d0=4, PROJ.
template <int C, int NL, bool PROJ>
__global__ __launch_bounds__(512, 2) void k23_kernel(
    const float* __restrict__ x, const unsigned short* __restrict__ Bsw,
    const float* __restrict__ biasWU, unsigned short* __restrict__ hbf,
    float* __restrict__ cbuf, int d0,
    const float* __restrict__ Wp, const float* __restrict__ bWp,
    float* __restrict__ out) {
    constexpr int TOTX = 2 * C - (C >> (NL - 1));
    constexpr int AR = (C < 16) ? 16 : C;
    __shared__ __align__(16) unsigned short xs[TOTX * XSTR];
    __shared__ __align__(16) unsigned short hA[AR * HSTR];
    __shared__ __align__(16) unsigned short hB[16 * HSTR];
    __shared__ __align__(16) float cA[AR * CSTR];
    __shared__ __align__(16) float cB[16 * CSTR];
    __shared__ float red[4][128];

    const int tid = threadIdx.x;
    const int w = tid >> 6, lane = tid & 63, L = lane & 15, q = lane >> 4;
    const int ch = w * 16 + L;

    short8 b[32];
#pragma unroll
    for (int t = 0; t < 32; ++t)
        b[t] = *(const short8*)(Bsw + ((size_t)w << 14) + (t << 9) + lane * 8);

    {
        int xoff = 0;
#pragma unroll
        for (int l = 0; l < NL; ++l) {
            const int rows = C >> l;
            const long base = ((1 << (d0 - l)) - 1) + (long)blockIdx.x * rows;
            for (int i = tid; i < rows * 32; i += 512) {
                const int row = i >> 5, j = i & 31;
                float4 v = *(const float4*)(x + (size_t)(base + row) * DIM + j * 4);
                ushort4 o;
                o.x = f2bf(v.x); o.y = f2bf(v.y); o.z = f2bf(v.z); o.w = f2bf(v.w);
                *(ushort4*)(xs + (xoff + row) * XSTR + j * 4) = o;
            }
            xoff += rows;
        }
    }
    __syncthreads();

    const long cb = ((1 << (d0 + 1)) - 1) + (long)blockIdx.x * (2 * C);
    internal_level<true>(xs, nullptr, nullptr, hbf, cbuf, cb,
                         hA, HSTR, cA, CSTR, C, b, biasWU, L, q, ch);
    __syncthreads();

    const unsigned short* hin = hA;
    const float* cin = cA;
    int xoff = C;
#pragma unroll
    for (int l = 1; l < NL; ++l) {
        const int cnt = C >> l;
        if (!PROJ && l == NL - 1) {
            const long ob = ((1 << (d0 - (NL - 1))) - 1) + (long)blockIdx.x;
            internal_level<false>(xs + xoff * XSTR, hin, cin, nullptr, nullptr, 0,
                                  hbf + (size_t)ob * DIM, DIM,
                                  cbuf + (size_t)ob * DIM, DIM, cnt, b, biasWU, L, q, ch);
        } else {
            unsigned short* ho = (l & 1) ? hB : hA;
            float* co = (l & 1) ? cB : cA;
            internal_level<false>(xs + xoff * XSTR, hin, cin, nullptr, nullptr, 0,
                                  ho, HSTR, co, CSTR, cnt, b, biasWU, L, q, ch);
            __syncthreads();
            hin = ho; cin = co;
        }
        xoff += cnt;
    }

    if (PROJ) {
        const int o = tid & 127, sg = tid >> 7;
        float pacc = 0.f;
#pragma unroll
        for (int jj = 0; jj < 8; ++jj) {
            const int k = sg * 32 + jj * 4;
            float4 wv = *(const float4*)(Wp + o * DIM + k);
            pacc += bf2f(hin[k]) * wv.x + bf2f(hin[k + 1]) * wv.y +
                    bf2f(hin[k + 2]) * wv.z + bf2f(hin[k + 3]) * wv.w;
        }
        red[sg][o] = pacc;
        __syncthreads();
        if (tid < 128) out[tid] = bWp[tid] + red[0][tid] + red[1][tid] + red[2][tid] + red[3][tid];
    }
}

extern "C" void kernel_launch(void* const* d_in, const int* in_sizes, int n_in,
                              void* d_out, int out_size, void* d_ws, size_t ws_size,
                              hipStream_t stream) {
    const float* x   = (const float*)d_in[0];
    const float* Wi  = (const float*)d_in[2];  const float* bWi = (const float*)d_in[3];
    const float* Ui  = (const float*)d_in[4];  const float* bUi = (const float*)d_in[5];
    const float* Wf  = (const float*)d_in[6];  const float* bWf = (const float*)d_in[7];
    const float* Uf  = (const float*)d_in[8];  const float* bUf = (const float*)d_in[9];
    const float* Wo  = (const float*)d_in[10]; const float* bWo = (const float*)d_in[11];
    const float* Uo  = (const float*)d_in[12]; const float* bUo = (const float*)d_in[13];
    const float* Wu  = (const float*)d_in[14]; const float* bWu = (const float*)d_in[15];
    const float* Uu  = (const float*)d_in[16]; const float* bUu = (const float*)d_in[17];
    const float* Wp  = (const float*)d_in[18]; const float* bWp = (const float*)d_in[19];

    // ws: Bsw (131072 bf16) | biasWU(512 f32) | biasL(512 f32) |
    //     cbuf (65536*128 f32 = 33.6 MB) | hbf (65536*128 bf16 = 16.8 MB)
    unsigned short* Bsw = (unsigned short*)d_ws;
    float* biasWU = (float*)(Bsw + 131072);
    float* biasL  = biasWU + 512;
    float* cbuf   = biasL + 512;
    unsigned short* hbf = (unsigned short*)(cbuf + (size_t)65536 * DIM);

    WPtrs p;
    p.W[0] = Wi; p.W[1] = Wo; p.W[2] = Wu; p.W[3] = Wf;
    p.U[0] = Ui; p.U[1] = Uo; p.U[2] = Uu; p.U[3] = Uf;
    p.bW[0] = bWi; p.bW[1] = bWo; p.bW[2] = bWu; p.bW[3] = bWf;
    p.bU[0] = bUi; p.bU[1] = bUo; p.bU[2] = bUu; p.bU[3] = bUf;

    prep_kernel<<<512, 256, 0, stream>>>(p, Bsw, biasWU, biasL);

    // K_A: d16 (leaves) + d15, 2048 tiles, persistent grid 256 x 8 tiles.
    kd2p_kernel<true><<<256, 512, 0, stream>>>(x, Bsw, biasL, biasWU, hbf, cbuf,
                                               (1 << 16) - 1, (1 << 15) - 1, 8);
    // K_B: d14 + d13 (children = d15), 512 tiles, grid 256 x 2.
    kd2p_kernel<false><<<256, 512, 0, stream>>>(x, Bsw, biasL, biasWU, hbf, cbuf,
                                                (1 << 14) - 1, (1 << 13) - 1, 2);
    // K_C: d12 + d11 (children = d13), 128 tiles, grid 128 x 1.
    kd2p_kernel<false><<<128, 512, 0, stream>>>(x, Bsw, biasL, biasWU, hbf, cbuf,
                                                (1 << 12) - 1, (1 << 11) - 1, 1);
    // K_D: d10..d5 (children = d11), 32 blocks.
    k23_kernel<32, 6, false><<<32, 512, 0, stream>>>(x, Bsw, biasWU, hbf, cbuf, 10,
                                                     nullptr, nullptr, nullptr);
    // K_E: d4..d0 + projection (children = d5).
    k23_kernel<16, 5, true><<<1, 512, 0, stream>>>(x, Bsw, biasWU, hbf, cbuf, 4,
                                                   Wp, bWp, (float*)d_out);
}